// Round 1
// baseline (75.593 us; speedup 1.0000x reference)
//
#include <hip/hip_runtime.h>
#include <cstdint>

// NT-Xent: B=4096, D=128, N=8192, T=0.5
// loss = mean_i( log(sum_{j!=i} exp(sim_ij/T)) - sim_{i,(i+B)%N}/T )
// sim = rownorm(z) @ rownorm(z)^T  (cosine similarity, bounded [-1,1])

#define BROWS 4096
#define NROWS 8192
#define DIMS  128
#define ROWB  256          // bytes per bf16 row (128*2)
#define CS    16           // column splits in main kernel
#define BC    128          // columns staged per iteration
#define BRT   256          // rows per block in main kernel

typedef __attribute__((ext_vector_type(8))) __bf16 bf16x8;
typedef __attribute__((ext_vector_type(4))) float  f32x4;

__device__ __forceinline__ uint16_t f2bf(float f) {
    // round-to-nearest-even f32 -> bf16 (inputs are finite)
    uint32_t u = __builtin_bit_cast(uint32_t, f);
    u = (u + 0x7FFFu + ((u >> 16) & 1u)) >> 16;
    return (uint16_t)u;
}
__device__ __forceinline__ float bf2f(uint16_t b) {
    return __builtin_bit_cast(float, ((uint32_t)b) << 16);
}

// ---------------- kernel 1: L2-normalize rows, emit bf16 zn [8192][128] ----
// 256 thr/block, 8 lanes per row (16 floats each), 32 rows/block, 256 blocks
__global__ __launch_bounds__(256) void k_normalize(
    const float* __restrict__ zi, const float* __restrict__ zj,
    uint16_t* __restrict__ zn)
{
    int tid  = threadIdx.x;
    int lane = tid & 63;
    int wid  = tid >> 6;
    int li   = lane & 7;                       // lane-in-row
    int row  = blockIdx.x * 32 + wid * 8 + (lane >> 3);

    const float* src = (row < BROWS) ? (zi + (size_t)row * DIMS)
                                     : (zj + (size_t)(row - BROWS) * DIMS);
    float4 v[4];
    const float4* s4 = (const float4*)(src + li * 16);
#pragma unroll
    for (int c = 0; c < 4; ++c) v[c] = s4[c];

    float ss = 0.f;
#pragma unroll
    for (int c = 0; c < 4; ++c)
        ss += v[c].x*v[c].x + v[c].y*v[c].y + v[c].z*v[c].z + v[c].w*v[c].w;
#pragma unroll
    for (int off = 1; off < 8; off <<= 1) ss += __shfl_xor(ss, off);

    float scale = 1.0f / fmaxf(sqrtf(ss), 1e-8f);

    float e[16];
#pragma unroll
    for (int c = 0; c < 4; ++c) {
        e[c*4+0] = v[c].x * scale; e[c*4+1] = v[c].y * scale;
        e[c*4+2] = v[c].z * scale; e[c*4+3] = v[c].w * scale;
    }
    uint32_t w[8];
#pragma unroll
    for (int q = 0; q < 8; ++q)
        w[q] = (uint32_t)f2bf(e[2*q]) | ((uint32_t)f2bf(e[2*q+1]) << 16);

    uint4* dst = (uint4*)((char*)zn + (size_t)row * ROWB + li * 32);
    dst[0] = make_uint4(w[0], w[1], w[2], w[3]);
    dst[1] = make_uint4(w[4], w[5], w[6], w[7]);
}

// ---------------- kernel 2: sim tiles via MFMA + online sum(exp) per row ----
// grid (32 row-blocks, 16 col-splits); block 256 thr = 4 waves x 64 rows.
// Each iteration stages BC=128 column-rows (32 KB) in LDS with XOR swizzle.
__global__ __launch_bounds__(256, 2) void k_simlse(
    const uint16_t* __restrict__ zn, float* __restrict__ partial)
{
    __shared__ __align__(16) char lds[BC * ROWB];   // 32 KB
    const char* znb = (const char*)zn;

    int tid  = threadIdx.x;
    int lane = tid & 63;
    int wid  = tid >> 6;
    int lo16 = lane & 15;
    int hi4  = lane >> 4;                       // 0..3
    int rowBase = blockIdx.x * BRT + wid * 64;
    int colSplitBase = blockIdx.y * (NROWS / CS);   // 512 cols per split

    // A fragments: 4 row-tiles x 4 K-frags, kept in registers for the kernel.
    // lane pattern: row = lo16, k-chunk = hi4*8 (+8 contiguous bf16)
    bf16x8 a[4][4];
#pragma unroll
    for (int rt = 0; rt < 4; ++rt) {
        int row = rowBase + rt * 16 + lo16;
#pragma unroll
        for (int kf = 0; kf < 4; ++kf) {
            uint4 v = *(const uint4*)(znb + (size_t)row * ROWB + kf * 64 + hi4 * 16);
            a[rt][kf] = __builtin_bit_cast(bf16x8, v);
        }
    }

    float rs[4][4];
#pragma unroll
    for (int rt = 0; rt < 4; ++rt)
#pragma unroll
        for (int r = 0; r < 4; ++r) rs[rt][r] = 0.f;

    const float K1 = 2.8853900817779268f;       // (1/T)*log2(e) = 2*1.4427

    for (int it = 0; it < (NROWS / CS) / BC; ++it) {   // 4 iterations
        int colBase = colSplitBase + it * BC;
        __syncthreads();
        // stage: 2048 16B chunks, 8 per thread, coalesced global reads,
        // XOR-swizzled LDS writes (bits 4..6 of in-row byte ^ row&7)
        const uint4* src = (const uint4*)(znb + (size_t)colBase * ROWB);
#pragma unroll
        for (int c = 0; c < 8; ++c) {
            int idx = tid + c * 256;
            int row = idx >> 4, cir = idx & 15;
            uint4 v = src[idx];
            int byt = row * ROWB + ((cir * 16) ^ ((row & 7) << 4));
            *(uint4*)(lds + byt) = v;
        }
        __syncthreads();

#pragma unroll
        for (int ct = 0; ct < 8; ++ct) {
            // B fragments (B^T rows == column vectors), same lane pattern as A
            bf16x8 b[4];
            int brow = ct * 16 + lo16;
#pragma unroll
            for (int kf = 0; kf < 4; ++kf) {
                int byt = brow * ROWB + ((kf * 64 + hi4 * 16) ^ ((brow & 7) << 4));
                b[kf] = __builtin_bit_cast(bf16x8, *(const uint4*)(lds + byt));
            }
#pragma unroll
            for (int rt = 0; rt < 4; ++rt) {
                f32x4 acc = {0.f, 0.f, 0.f, 0.f};
#pragma unroll
                for (int kf = 0; kf < 4; ++kf)
                    acc = __builtin_amdgcn_mfma_f32_16x16x32_bf16(a[rt][kf], b[kf], acc, 0, 0, 0);
                // C/D layout: col = lane&15, row = (lane>>4)*4 + r   [m89/m91]
                int gr0 = rowBase + rt * 16 + hi4 * 4;
                int gc  = colBase + ct * 16 + lo16;
#pragma unroll
                for (int r = 0; r < 4; ++r) {
                    float ev = exp2f(acc[r] * K1);   // sim bounded [-1,1]: no max needed
                    if (gr0 + r == gc) ev = 0.f;     // diagonal mask
                    rs[rt][r] += ev;
                }
            }
        }
    }

    // reduce partial sums across the 16 column-lanes of each quad-group
#pragma unroll
    for (int rt = 0; rt < 4; ++rt)
#pragma unroll
        for (int r = 0; r < 4; ++r) {
            float s = rs[rt][r];
            s += __shfl_xor(s, 1);  s += __shfl_xor(s, 2);
            s += __shfl_xor(s, 4);  s += __shfl_xor(s, 8);
            if (lo16 == 0) {
                int row = rowBase + rt * 16 + hi4 * 4 + r;
                partial[blockIdx.y * NROWS + row] = s;
            }
        }
}

// ---------------- kernel 3: per-row lse - pos, block partial sums ----------
__global__ __launch_bounds__(256) void k_finalize(
    const uint16_t* __restrict__ zn, const float* __restrict__ partial,
    float* __restrict__ blocksum)
{
    int tid = threadIdx.x;
    int i = blockIdx.x * 256 + tid;

    float S = 0.f;
#pragma unroll
    for (int cs = 0; cs < CS; ++cs) S += partial[cs * NROWS + i];
    float lse = logf(S);

    int j = (i + BROWS) & (NROWS - 1);
    const uint4* ri = (const uint4*)((const char*)zn + (size_t)i * ROWB);
    const uint4* rj = (const uint4*)((const char*)zn + (size_t)j * ROWB);
    float dot = 0.f;
#pragma unroll
    for (int c = 0; c < 16; ++c) {
        uint4 u = ri[c], v = rj[c];
        const uint32_t* pu = (const uint32_t*)&u;
        const uint32_t* pv = (const uint32_t*)&v;
#pragma unroll
        for (int q = 0; q < 4; ++q) {
            dot += bf2f((uint16_t)(pu[q] & 0xffffu)) * bf2f((uint16_t)(pv[q] & 0xffffu));
            dot += bf2f((uint16_t)(pu[q] >> 16))     * bf2f((uint16_t)(pv[q] >> 16));
        }
    }
    float c = lse - 2.0f * dot;   // pos = sim/T = dot*2

#pragma unroll
    for (int off = 1; off < 64; off <<= 1) c += __shfl_xor(c, off);
    __shared__ float wsum[4];
    int lane = tid & 63, wid = tid >> 6;
    if (lane == 0) wsum[wid] = c;
    __syncthreads();
    if (tid == 0) blocksum[blockIdx.x] = wsum[0] + wsum[1] + wsum[2] + wsum[3];
}

// ---------------- kernel 4: final scalar --------------------------------
__global__ __launch_bounds__(64) void k_reduce(
    const float* __restrict__ blocksum, float* __restrict__ out)
{
    int tid = threadIdx.x;
    float v = (tid < 32) ? blocksum[tid] : 0.f;
#pragma unroll
    for (int off = 1; off < 64; off <<= 1) v += __shfl_xor(v, off);
    if (tid == 0) out[0] = v * (1.0f / (float)NROWS);
}

extern "C" void kernel_launch(void* const* d_in, const int* in_sizes, int n_in,
                              void* d_out, int out_size, void* d_ws, size_t ws_size,
                              hipStream_t stream)
{
    const float* zi = (const float*)d_in[0];
    const float* zj = (const float*)d_in[1];
    float* out = (float*)d_out;

    char* ws = (char*)d_ws;
    uint16_t* zn     = (uint16_t*)ws;                                   // 2 MB
    float*    partial  = (float*)(ws + (size_t)NROWS * ROWB);           // 512 KB
    float*    blocksum = (float*)(ws + (size_t)NROWS * ROWB + (size_t)CS * NROWS * 4);

    k_normalize<<<dim3(256), dim3(256), 0, stream>>>(zi, zj, zn);
    k_simlse  <<<dim3(32, CS), dim3(256), 0, stream>>>(zn, partial);
    k_finalize<<<dim3(32), dim3(256), 0, stream>>>(zn, partial, blocksum);
    k_reduce  <<<dim3(1), dim3(64), 0, stream>>>(blocksum, out);
}

// Round 2
// 57.022 us; speedup vs baseline: 1.3257x; 1.3257x over previous
//
#include <hip/hip_runtime.h>
#include <cstdint>

// NT-Xent: B=4096, D=128, N=8192, T=0.5
// loss = mean_i( log(sum_{j!=i} exp(sim_ij/T)) - sim_{i,(i+B)%N}/T )
// sim = rownorm(z) @ rownorm(z)^T  (cosine similarity, bounded [-1,1])
//
// R1 -> R2 changes (theory: latency-bound, not pipe-bound):
//  - drop LDS staging entirely (zn = 2 MB, L2-resident; staging was overhead)
//  - grid 512 -> 1024 blocks (4 blocks/CU), launch_bounds(256,4)
//  - diagonal mask removed from hot loop; subtracted analytically in finalize
//  - __builtin_amdgcn_exp2f for a bare v_exp_f32

#define BROWS 4096
#define NROWS 8192
#define DIMS  128
#define ROWB  256          // bytes per bf16 row (128*2)
#define CS    32           // column splits
#define BCOLS 256          // cols per block (NROWS/CS)
#define BRT   256          // rows per block

typedef __attribute__((ext_vector_type(8))) __bf16 bf16x8;
typedef __attribute__((ext_vector_type(4))) float  f32x4;

__device__ __forceinline__ uint16_t f2bf(float f) {
    uint32_t u = __builtin_bit_cast(uint32_t, f);
    u = (u + 0x7FFFu + ((u >> 16) & 1u)) >> 16;
    return (uint16_t)u;
}
__device__ __forceinline__ float bf2f(uint16_t b) {
    return __builtin_bit_cast(float, ((uint32_t)b) << 16);
}

// ---------------- kernel 1: L2-normalize rows, emit bf16 zn [8192][128] ----
__global__ __launch_bounds__(256) void k_normalize(
    const float* __restrict__ zi, const float* __restrict__ zj,
    uint16_t* __restrict__ zn)
{
    int tid  = threadIdx.x;
    int lane = tid & 63;
    int wid  = tid >> 6;
    int li   = lane & 7;                       // lane-in-row
    int row  = blockIdx.x * 32 + wid * 8 + (lane >> 3);

    const float* src = (row < BROWS) ? (zi + (size_t)row * DIMS)
                                     : (zj + (size_t)(row - BROWS) * DIMS);
    float4 v[4];
    const float4* s4 = (const float4*)(src + li * 16);
#pragma unroll
    for (int c = 0; c < 4; ++c) v[c] = s4[c];

    float ss = 0.f;
#pragma unroll
    for (int c = 0; c < 4; ++c)
        ss += v[c].x*v[c].x + v[c].y*v[c].y + v[c].z*v[c].z + v[c].w*v[c].w;
#pragma unroll
    for (int off = 1; off < 8; off <<= 1) ss += __shfl_xor(ss, off);

    float scale = 1.0f / fmaxf(sqrtf(ss), 1e-8f);

    float e[16];
#pragma unroll
    for (int c = 0; c < 4; ++c) {
        e[c*4+0] = v[c].x * scale; e[c*4+1] = v[c].y * scale;
        e[c*4+2] = v[c].z * scale; e[c*4+3] = v[c].w * scale;
    }
    uint32_t w[8];
#pragma unroll
    for (int q = 0; q < 8; ++q)
        w[q] = (uint32_t)f2bf(e[2*q]) | ((uint32_t)f2bf(e[2*q+1]) << 16);

    uint4* dst = (uint4*)((char*)zn + (size_t)row * ROWB + li * 32);
    dst[0] = make_uint4(w[0], w[1], w[2], w[3]);
    dst[1] = make_uint4(w[4], w[5], w[6], w[7]);
}

// ---------------- kernel 2: sim tiles via MFMA + online sum(exp) per row ----
// grid (32 row-blocks, 32 col-splits); block = 4 waves; wave = 64 rows x 256 cols.
// No LDS: B fragments loaded straight from global (L2-resident), reg-prefetched.
// No diagonal masking here: full row-sum; diag term subtracted in k_finalize.
__global__ __launch_bounds__(256, 4) void k_simlse(
    const uint16_t* __restrict__ zn, float* __restrict__ partial)
{
    const char* znb = (const char*)zn;
    int tid  = threadIdx.x;
    int lane = tid & 63;
    int wid  = tid >> 6;
    int lo16 = lane & 15;
    int hi4  = lane >> 4;                       // 0..3
    int rowBase = blockIdx.x * BRT + wid * 64;
    int colBase = blockIdx.y * BCOLS;

    // A fragments: 4 row-tiles x 4 K-frags (64 VGPR), held for whole kernel.
    bf16x8 a[4][4];
#pragma unroll
    for (int rt = 0; rt < 4; ++rt) {
        const char* ap = znb + (size_t)(rowBase + rt * 16 + lo16) * ROWB + hi4 * 16;
#pragma unroll
        for (int kf = 0; kf < 4; ++kf)
            a[rt][kf] = __builtin_bit_cast(bf16x8, *(const uint4*)(ap + kf * 64));
    }

    float rs[4][4];
#pragma unroll
    for (int rt = 0; rt < 4; ++rt)
#pragma unroll
        for (int r = 0; r < 4; ++r) rs[rt][r] = 0.f;

    const float K1 = 2.8853900817779268f;       // (1/T)*log2(e)

    // B fragment base for this wave: row = colBase + ct*16 + lo16, byte hi4*16 + kf*64
    const char* bp = znb + (size_t)(colBase + lo16) * ROWB + hi4 * 16;

    uint4 bv[4];
#pragma unroll
    for (int kf = 0; kf < 4; ++kf) bv[kf] = *(const uint4*)(bp + kf * 64);

    for (int ct = 0; ct < BCOLS / 16; ++ct) {
        // prefetch next ct's B fragments (clamped: last iter re-reads, discarded)
        int nct = (ct + 1 < BCOLS / 16) ? (ct + 1) : ct;
        const char* bq = bp + (size_t)nct * 16 * ROWB;
        uint4 bn[4];
#pragma unroll
        for (int kf = 0; kf < 4; ++kf) bn[kf] = *(const uint4*)(bq + kf * 64);

        bf16x8 b[4];
#pragma unroll
        for (int kf = 0; kf < 4; ++kf) b[kf] = __builtin_bit_cast(bf16x8, bv[kf]);

#pragma unroll
        for (int rt = 0; rt < 4; ++rt) {
            f32x4 acc = {0.f, 0.f, 0.f, 0.f};
#pragma unroll
            for (int kf = 0; kf < 4; ++kf)
                acc = __builtin_amdgcn_mfma_f32_16x16x32_bf16(a[rt][kf], b[kf], acc, 0, 0, 0);
            // C/D layout: col = lane&15, row = (lane>>4)*4 + r   [m89/m91]
#pragma unroll
            for (int r = 0; r < 4; ++r)
                rs[rt][r] += __builtin_amdgcn_exp2f(acc[r] * K1);
        }

#pragma unroll
        for (int kf = 0; kf < 4; ++kf) bv[kf] = bn[kf];
    }

    // reduce partial sums across the 16 column-lanes
#pragma unroll
    for (int rt = 0; rt < 4; ++rt)
#pragma unroll
        for (int r = 0; r < 4; ++r) {
            float s = rs[rt][r];
            s += __shfl_xor(s, 1);  s += __shfl_xor(s, 2);
            s += __shfl_xor(s, 4);  s += __shfl_xor(s, 8);
            if (lo16 == 0) {
                int row = rowBase + rt * 16 + hi4 * 4 + r;
                partial[blockIdx.y * NROWS + row] = s;
            }
        }
}

// ---------------- kernel 3: per-row lse - pos, subtract diag, block sums ----
__global__ __launch_bounds__(256) void k_finalize(
    const uint16_t* __restrict__ zn, const float* __restrict__ partial,
    float* __restrict__ blocksum)
{
    int tid = threadIdx.x;
    int i = blockIdx.x * 256 + tid;

    float S = 0.f;
#pragma unroll
    for (int cs = 0; cs < CS; ++cs) S += partial[cs * NROWS + i];

    int j = (i + BROWS) & (NROWS - 1);
    const uint4* ri = (const uint4*)((const char*)zn + (size_t)i * ROWB);
    const uint4* rj = (const uint4*)((const char*)zn + (size_t)j * ROWB);
    float pdot = 0.f;   // <zn_i, zn_j>
    float sdot = 0.f;   // <zn_i, zn_i>  (same values MFMA saw, fp32-summed)
#pragma unroll
    for (int c = 0; c < 16; ++c) {
        uint4 u = ri[c], v = rj[c];
        const uint32_t* pu = (const uint32_t*)&u;
        const uint32_t* pv = (const uint32_t*)&v;
#pragma unroll
        for (int q = 0; q < 4; ++q) {
            float u0 = bf2f((uint16_t)(pu[q] & 0xffffu)), u1 = bf2f((uint16_t)(pu[q] >> 16));
            float v0 = bf2f((uint16_t)(pv[q] & 0xffffu)), v1 = bf2f((uint16_t)(pv[q] >> 16));
            pdot += u0 * v0 + u1 * v1;
            sdot += u0 * u0 + u1 * u1;
        }
    }
    const float K1 = 2.8853900817779268f;
    S -= __builtin_amdgcn_exp2f(sdot * K1);          // remove diagonal term
    float lse = __builtin_amdgcn_logf(S) * 0.69314718055994531f;
    float c = lse - 2.0f * pdot;                     // pos = sim/T = dot/T

#pragma unroll
    for (int off = 1; off < 64; off <<= 1) c += __shfl_xor(c, off);
    __shared__ float wsum[4];
    int lane = tid & 63, wid = tid >> 6;
    if (lane == 0) wsum[wid] = c;
    __syncthreads();
    if (tid == 0) blocksum[blockIdx.x] = wsum[0] + wsum[1] + wsum[2] + wsum[3];
}

// ---------------- kernel 4: final scalar --------------------------------
__global__ __launch_bounds__(64) void k_reduce(
    const float* __restrict__ blocksum, float* __restrict__ out)
{
    int tid = threadIdx.x;
    float v = (tid < 32) ? blocksum[tid] : 0.f;
#pragma unroll
    for (int off = 1; off < 64; off <<= 1) v += __shfl_xor(v, off);
    if (tid == 0) out[0] = v * (1.0f / (float)NROWS);
}

extern "C" void kernel_launch(void* const* d_in, const int* in_sizes, int n_in,
                              void* d_out, int out_size, void* d_ws, size_t ws_size,
                              hipStream_t stream)
{
    const float* zi = (const float*)d_in[0];
    const float* zj = (const float*)d_in[1];
    float* out = (float*)d_out;

    char* ws = (char*)d_ws;
    uint16_t* zn       = (uint16_t*)ws;                                  // 2 MB
    float*    partial  = (float*)(ws + (size_t)NROWS * ROWB);            // 1 MB
    float*    blocksum = (float*)(ws + (size_t)NROWS * ROWB + (size_t)CS * NROWS * 4);

    k_normalize<<<dim3(256), dim3(256), 0, stream>>>(zi, zj, zn);
    k_simlse  <<<dim3(32, CS), dim3(256), 0, stream>>>(zn, partial);
    k_finalize<<<dim3(32), dim3(256), 0, stream>>>(zn, partial, blocksum);
    k_reduce  <<<dim3(1), dim3(64), 0, stream>>>(blocksum, out);
}

// Round 3
// 56.028 us; speedup vs baseline: 1.3492x; 1.0177x over previous
//
#include <hip/hip_runtime.h>
#include <cstdint>

// NT-Xent: B=4096, D=128, N=8192, T=0.5
// loss = mean_i( log(sum_{j!=i} exp(sim_ij/T)) - sim_{i,(i+B)%N}/T )
//
// R2 -> R3 (theory: R2 was a regalloc pathology — VGPR=64 forced A-fragment
// reload per iteration):
//  - launch_bounds(256,3): VGPR cap ~168 so A (64 regs) + B dbuf stay resident
//  - grid 768 = 256 CU x 3 blocks, fully resident single round (ragged col split)
//  - named b0/b1 depth-2 software pipeline (no runtime-indexed buffers)
//  - znA prescaled by K1=(1/T)*log2(e): epilogue is bare v_exp_f32 + v_add

#define BROWS 4096
#define NROWS 8192
#define DIMS  128
#define ROWB  256          // bytes per bf16 row
#define CSPL  24           // column splits: 32 rowblocks x 24 = 768 blocks
#define CTILES 512         // 8192/16 column tiles
#define BRT   256          // rows per block (4 waves x 64)

typedef __attribute__((ext_vector_type(8))) __bf16 bf16x8;
typedef __attribute__((ext_vector_type(4))) float  f32x4;

#define K1F 2.8853900817779268f   // (1/T)*log2(e)
#define LN2F 0.69314718055994531f

__device__ __forceinline__ uint16_t f2bf(float f) {
    uint32_t u = __builtin_bit_cast(uint32_t, f);
    u = (u + 0x7FFFu + ((u >> 16) & 1u)) >> 16;
    return (uint16_t)u;
}
__device__ __forceinline__ float bf2f(uint16_t b) {
    return __builtin_bit_cast(float, ((uint32_t)b) << 16);
}

// ---- kernel 1: L2-normalize rows; emit znB = bf16(x^), znA = bf16(K1*x^) ----
__global__ __launch_bounds__(256) void k_normalize(
    const float* __restrict__ zi, const float* __restrict__ zj,
    uint16_t* __restrict__ znA, uint16_t* __restrict__ znB)
{
    int tid  = threadIdx.x;
    int lane = tid & 63;
    int wid  = tid >> 6;
    int li   = lane & 7;
    int row  = blockIdx.x * 32 + wid * 8 + (lane >> 3);

    const float* src = (row < BROWS) ? (zi + (size_t)row * DIMS)
                                     : (zj + (size_t)(row - BROWS) * DIMS);
    float4 v[4];
    const float4* s4 = (const float4*)(src + li * 16);
#pragma unroll
    for (int c = 0; c < 4; ++c) v[c] = s4[c];

    float ss = 0.f;
#pragma unroll
    for (int c = 0; c < 4; ++c)
        ss += v[c].x*v[c].x + v[c].y*v[c].y + v[c].z*v[c].z + v[c].w*v[c].w;
#pragma unroll
    for (int off = 1; off < 8; off <<= 1) ss += __shfl_xor(ss, off);

    float scale = 1.0f / fmaxf(sqrtf(ss), 1e-8f);

    float e[16];
#pragma unroll
    for (int c = 0; c < 4; ++c) {
        e[c*4+0] = v[c].x * scale; e[c*4+1] = v[c].y * scale;
        e[c*4+2] = v[c].z * scale; e[c*4+3] = v[c].w * scale;
    }
    uint32_t wB[8], wA[8];
#pragma unroll
    for (int q = 0; q < 8; ++q) {
        wB[q] = (uint32_t)f2bf(e[2*q])       | ((uint32_t)f2bf(e[2*q+1])       << 16);
        wA[q] = (uint32_t)f2bf(e[2*q] * K1F) | ((uint32_t)f2bf(e[2*q+1] * K1F) << 16);
    }
    uint4* dB = (uint4*)((char*)znB + (size_t)row * ROWB + li * 32);
    dB[0] = make_uint4(wB[0], wB[1], wB[2], wB[3]);
    dB[1] = make_uint4(wB[4], wB[5], wB[6], wB[7]);
    uint4* dA = (uint4*)((char*)znA + (size_t)row * ROWB + li * 32);
    dA[0] = make_uint4(wA[0], wA[1], wA[2], wA[3]);
    dA[1] = make_uint4(wA[4], wA[5], wA[6], wA[7]);
}

// ---- kernel 2: sim tiles via MFMA + sum(exp) per row ------------------------
// grid (32 rowblocks, 24 colsplits) = 768 blocks = 3/CU, fully resident.
// Wave: 64 rows x (21..22) 16-col tiles. A resident in regs; B depth-2 pipelined.
__global__ __launch_bounds__(256, 3) void k_simlse(
    const uint16_t* __restrict__ znA, const uint16_t* __restrict__ znB,
    float* __restrict__ partial)
{
    const char* zA = (const char*)znA;
    const char* zB = (const char*)znB;
    int tid  = threadIdx.x;
    int lane = tid & 63;
    int wid  = tid >> 6;
    int lo16 = lane & 15;
    int hi4  = lane >> 4;
    int rowBase = blockIdx.x * BRT + wid * 64;

    // A fragments (prescaled by K1): 4 row-tiles x 4 K-frags = 64 VGPR, resident.
    bf16x8 a[4][4];
#pragma unroll
    for (int rt = 0; rt < 4; ++rt) {
        const char* ap = zA + (size_t)(rowBase + rt * 16 + lo16) * ROWB + hi4 * 16;
#pragma unroll
        for (int kf = 0; kf < 4; ++kf)
            a[rt][kf] = __builtin_bit_cast(bf16x8, *(const uint4*)(ap + kf * 64));
    }

    float rs[4][4];
#pragma unroll
    for (int rt = 0; rt < 4; ++rt)
#pragma unroll
        for (int r = 0; r < 4; ++r) rs[rt][r] = 0.f;

    // ragged col-tile range for this split (21 or 22 tiles)
    int t0 = (CTILES * blockIdx.y) / CSPL;
    int t1 = (CTILES * (blockIdx.y + 1)) / CSPL;
    int nt = t1 - t0;

    const char* bbase = zB + (size_t)(t0 * 16 + lo16) * ROWB + hi4 * 16;

#define LOADB(buf, t) do { const char* p_ = bbase + (size_t)(t) * (16 * ROWB); \
        buf[0] = *(const uint4*)(p_);       buf[1] = *(const uint4*)(p_ + 64);  \
        buf[2] = *(const uint4*)(p_ + 128); buf[3] = *(const uint4*)(p_ + 192); } while (0)

#define COMPUTE(buf) do {                                                        \
        bf16x8 b_[4];                                                            \
        b_[0] = __builtin_bit_cast(bf16x8, buf[0]);                              \
        b_[1] = __builtin_bit_cast(bf16x8, buf[1]);                              \
        b_[2] = __builtin_bit_cast(bf16x8, buf[2]);                              \
        b_[3] = __builtin_bit_cast(bf16x8, buf[3]);                              \
        _Pragma("unroll")                                                        \
        for (int rt = 0; rt < 4; ++rt) {                                         \
            f32x4 acc = {0.f, 0.f, 0.f, 0.f};                                    \
            _Pragma("unroll")                                                    \
            for (int kf = 0; kf < 4; ++kf)                                       \
                acc = __builtin_amdgcn_mfma_f32_16x16x32_bf16(a[rt][kf], b_[kf], acc, 0, 0, 0); \
            _Pragma("unroll")                                                    \
            for (int r = 0; r < 4; ++r)                                          \
                rs[rt][r] += __builtin_amdgcn_exp2f(acc[r]);                     \
        }                                                                        \
    } while (0)

    uint4 b0[4], b1[4];
    LOADB(b0, 0);
    LOADB(b1, 1);          // nt >= 21 always, so tile 1 exists

    int t = 0;
    for (; t + 2 < nt; t += 2) {
        COMPUTE(b0);
        LOADB(b0, t + 2);
        COMPUTE(b1);
        if (t + 3 < nt) LOADB(b1, t + 3);
    }
    COMPUTE(b0);
    if (t + 1 < nt) COMPUTE(b1);

#undef LOADB
#undef COMPUTE

    // reduce row-sums across the 16 column-lanes; write per-split partials
#pragma unroll
    for (int rt = 0; rt < 4; ++rt)
#pragma unroll
        for (int r = 0; r < 4; ++r) {
            float s = rs[rt][r];
            s += __shfl_xor(s, 1);  s += __shfl_xor(s, 2);
            s += __shfl_xor(s, 4);  s += __shfl_xor(s, 8);
            if (lo16 == 0) {
                int row = rowBase + rt * 16 + hi4 * 4 + r;
                partial[blockIdx.y * NROWS + row] = s;
            }
        }
}

// ---- kernel 3: per-row lse - pos, subtract diag, block partial sums --------
__global__ __launch_bounds__(256) void k_finalize(
    const uint16_t* __restrict__ znA, const uint16_t* __restrict__ znB,
    const float* __restrict__ partial, float* __restrict__ blocksum)
{
    int tid = threadIdx.x;
    int i = blockIdx.x * 256 + tid;

    float S = 0.f;
#pragma unroll
    for (int cs = 0; cs < CSPL; ++cs) S += partial[cs * NROWS + i];

    int j = (i + BROWS) & (NROWS - 1);
    const uint4* rAi = (const uint4*)((const char*)znA + (size_t)i * ROWB);
    const uint4* rBi = (const uint4*)((const char*)znB + (size_t)i * ROWB);
    const uint4* rBj = (const uint4*)((const char*)znB + (size_t)j * ROWB);
    float adot = 0.f;   // K1 * <zn_i, zn_j>  (scaled pos logit, log2-space)
    float sdot = 0.f;   // K1 * <zn_i, zn_i>  (scaled diag logit)
#pragma unroll
    for (int c = 0; c < 16; ++c) {
        uint4 ua = rAi[c], ub = rBi[c], vb = rBj[c];
        const uint32_t* pa = (const uint32_t*)&ua;
        const uint32_t* pb = (const uint32_t*)&ub;
        const uint32_t* pv = (const uint32_t*)&vb;
#pragma unroll
        for (int q = 0; q < 4; ++q) {
            float a0 = bf2f((uint16_t)(pa[q] & 0xffffu)), a1 = bf2f((uint16_t)(pa[q] >> 16));
            float b0 = bf2f((uint16_t)(pb[q] & 0xffffu)), b1 = bf2f((uint16_t)(pb[q] >> 16));
            float v0 = bf2f((uint16_t)(pv[q] & 0xffffu)), v1 = bf2f((uint16_t)(pv[q] >> 16));
            adot += a0 * v0 + a1 * v1;
            sdot += a0 * b0 + a1 * b1;
        }
    }
    S -= __builtin_amdgcn_exp2f(sdot);                 // remove diagonal term
    float c = LN2F * (__builtin_amdgcn_logf(S) - adot); // ln(S) - pos/T

#pragma unroll
    for (int off = 1; off < 64; off <<= 1) c += __shfl_xor(c, off);
    __shared__ float wsum[4];
    int lane = tid & 63, wid = tid >> 6;
    if (lane == 0) wsum[wid] = c;
    __syncthreads();
    if (tid == 0) blocksum[blockIdx.x] = wsum[0] + wsum[1] + wsum[2] + wsum[3];
}

// ---- kernel 4: final scalar -------------------------------------------------
__global__ __launch_bounds__(64) void k_reduce(
    const float* __restrict__ blocksum, float* __restrict__ out)
{
    int tid = threadIdx.x;
    float v = (tid < 32) ? blocksum[tid] : 0.f;
#pragma unroll
    for (int off = 1; off < 64; off <<= 1) v += __shfl_xor(v, off);
    if (tid == 0) out[0] = v * (1.0f / (float)NROWS);
}

extern "C" void kernel_launch(void* const* d_in, const int* in_sizes, int n_in,
                              void* d_out, int out_size, void* d_ws, size_t ws_size,
                              hipStream_t stream)
{
    const float* zi = (const float*)d_in[0];
    const float* zj = (const float*)d_in[1];
    float* out = (float*)d_out;

    char* ws = (char*)d_ws;
    uint16_t* znA      = (uint16_t*)ws;                                   // 2 MB
    uint16_t* znB      = (uint16_t*)(ws + (size_t)NROWS * ROWB);          // 2 MB
    float*    partial  = (float*)(ws + 2 * (size_t)NROWS * ROWB);         // 768 KB
    float*    blocksum = (float*)(ws + 2 * (size_t)NROWS * ROWB
                                     + (size_t)CSPL * NROWS * 4);

    k_normalize<<<dim3(256), dim3(256), 0, stream>>>(zi, zj, znA, znB);
    k_simlse  <<<dim3(32, CSPL), dim3(256), 0, stream>>>(znA, znB, partial);
    k_finalize<<<dim3(32), dim3(256), 0, stream>>>(znA, znB, partial, blocksum);
    k_reduce  <<<dim3(1), dim3(64), 0, stream>>>(blocksum, out);
}

// Round 4
// 55.772 us; speedup vs baseline: 1.3554x; 1.0046x over previous
//
#include <hip/hip_runtime.h>
#include <cstdint>

// NT-Xent: B=4096, D=128, N=8192, T=0.5
// loss = mean_i( log(sum_{j!=i} exp(sim_ij/T)) - sim_{i,(i+B)%N}/T )
//
// R3 -> R4 (theory: allocator REMATERIALIZES the invariant A-loads inside the
// tile loop — VGPR=76 proves A isn't resident; every tile eats an exposed
// L2-latency chain):
//  - pin A fragments with empty inline-asm "+v" after load (remat-proof)
//  - everything else unchanged (structure was right, regalloc wasn't)

#define BROWS 4096
#define NROWS 8192
#define DIMS  128
#define ROWB  256          // bytes per bf16 row
#define CSPL  24           // column splits: 32 rowblocks x 24 = 768 blocks
#define CTILES 512         // 8192/16 column tiles
#define BRT   256          // rows per block (4 waves x 64)

typedef __attribute__((ext_vector_type(8))) __bf16    bf16x8;
typedef __attribute__((ext_vector_type(4))) float     f32x4;
typedef __attribute__((ext_vector_type(4))) uint32_t  u32x4;

#define K1F 2.8853900817779268f   // (1/T)*log2(e)
#define LN2F 0.69314718055994531f

__device__ __forceinline__ uint16_t f2bf(float f) {
    uint32_t u = __builtin_bit_cast(uint32_t, f);
    u = (u + 0x7FFFu + ((u >> 16) & 1u)) >> 16;
    return (uint16_t)u;
}
__device__ __forceinline__ float bf2f(uint16_t b) {
    return __builtin_bit_cast(float, ((uint32_t)b) << 16);
}

// ---- kernel 1: L2-normalize rows; emit znB = bf16(x^), znA = bf16(K1*x^) ----
__global__ __launch_bounds__(256) void k_normalize(
    const float* __restrict__ zi, const float* __restrict__ zj,
    uint16_t* __restrict__ znA, uint16_t* __restrict__ znB)
{
    int tid  = threadIdx.x;
    int lane = tid & 63;
    int wid  = tid >> 6;
    int li   = lane & 7;
    int row  = blockIdx.x * 32 + wid * 8 + (lane >> 3);

    const float* src = (row < BROWS) ? (zi + (size_t)row * DIMS)
                                     : (zj + (size_t)(row - BROWS) * DIMS);
    float4 v[4];
    const float4* s4 = (const float4*)(src + li * 16);
#pragma unroll
    for (int c = 0; c < 4; ++c) v[c] = s4[c];

    float ss = 0.f;
#pragma unroll
    for (int c = 0; c < 4; ++c)
        ss += v[c].x*v[c].x + v[c].y*v[c].y + v[c].z*v[c].z + v[c].w*v[c].w;
#pragma unroll
    for (int off = 1; off < 8; off <<= 1) ss += __shfl_xor(ss, off);

    float scale = 1.0f / fmaxf(sqrtf(ss), 1e-8f);

    float e[16];
#pragma unroll
    for (int c = 0; c < 4; ++c) {
        e[c*4+0] = v[c].x * scale; e[c*4+1] = v[c].y * scale;
        e[c*4+2] = v[c].z * scale; e[c*4+3] = v[c].w * scale;
    }
    uint32_t wB[8], wA[8];
#pragma unroll
    for (int q = 0; q < 8; ++q) {
        wB[q] = (uint32_t)f2bf(e[2*q])       | ((uint32_t)f2bf(e[2*q+1])       << 16);
        wA[q] = (uint32_t)f2bf(e[2*q] * K1F) | ((uint32_t)f2bf(e[2*q+1] * K1F) << 16);
    }
    uint4* dB = (uint4*)((char*)znB + (size_t)row * ROWB + li * 32);
    dB[0] = make_uint4(wB[0], wB[1], wB[2], wB[3]);
    dB[1] = make_uint4(wB[4], wB[5], wB[6], wB[7]);
    uint4* dA = (uint4*)((char*)znA + (size_t)row * ROWB + li * 32);
    dA[0] = make_uint4(wA[0], wA[1], wA[2], wA[3]);
    dA[1] = make_uint4(wA[4], wA[5], wA[6], wA[7]);
}

// ---- kernel 2: sim tiles via MFMA + sum(exp) per row ------------------------
// grid (32 rowblocks, 24 colsplits) = 768 blocks = 3/CU, fully resident.
// A pinned in regs via asm (remat-proof); B depth-2 software pipeline.
__global__ __launch_bounds__(256, 3) void k_simlse(
    const uint16_t* __restrict__ znA, const uint16_t* __restrict__ znB,
    float* __restrict__ partial)
{
    const char* zA = (const char*)znA;
    const char* zB = (const char*)znB;
    int tid  = threadIdx.x;
    int lane = tid & 63;
    int wid  = tid >> 6;
    int lo16 = lane & 15;
    int hi4  = lane >> 4;
    int rowBase = blockIdx.x * BRT + wid * 64;

    // A fragments (prescaled by K1): 4 row-tiles x 4 K-frags = 64 VGPR.
    u32x4 a[4][4];
#pragma unroll
    for (int rt = 0; rt < 4; ++rt) {
        const char* ap = zA + (size_t)(rowBase + rt * 16 + lo16) * ROWB + hi4 * 16;
#pragma unroll
        for (int kf = 0; kf < 4; ++kf)
            a[rt][kf] = *(const u32x4*)(ap + kf * 64);
    }
    // PIN: opaque identity — the allocator can neither rematerialize the
    // loads nor sink them into the loop. A stays in 64 live VGPRs.
#pragma unroll
    for (int rt = 0; rt < 4; ++rt)
#pragma unroll
        for (int kf = 0; kf < 4; ++kf)
            asm volatile("" : "+v"(a[rt][kf]));

    float rs[4][4];
#pragma unroll
    for (int rt = 0; rt < 4; ++rt)
#pragma unroll
        for (int r = 0; r < 4; ++r) rs[rt][r] = 0.f;

    // ragged col-tile range for this split (21 or 22 tiles)
    int t0 = (CTILES * blockIdx.y) / CSPL;
    int t1 = (CTILES * (blockIdx.y + 1)) / CSPL;
    int nt = t1 - t0;

    const char* bbase = zB + (size_t)(t0 * 16 + lo16) * ROWB + hi4 * 16;

#define LOADB(buf, t) do { const char* p_ = bbase + (size_t)(t) * (16 * ROWB); \
        buf[0] = *(const u32x4*)(p_);       buf[1] = *(const u32x4*)(p_ + 64);  \
        buf[2] = *(const u32x4*)(p_ + 128); buf[3] = *(const u32x4*)(p_ + 192); } while (0)

#define COMPUTE(buf) do {                                                        \
        _Pragma("unroll")                                                        \
        for (int rt = 0; rt < 4; ++rt) {                                         \
            f32x4 acc = {0.f, 0.f, 0.f, 0.f};                                    \
            _Pragma("unroll")                                                    \
            for (int kf = 0; kf < 4; ++kf)                                       \
                acc = __builtin_amdgcn_mfma_f32_16x16x32_bf16(                   \
                        __builtin_bit_cast(bf16x8, a[rt][kf]),                   \
                        __builtin_bit_cast(bf16x8, buf[kf]), acc, 0, 0, 0);      \
            _Pragma("unroll")                                                    \
            for (int r = 0; r < 4; ++r)                                          \
                rs[rt][r] += __builtin_amdgcn_exp2f(acc[r]);                     \
        }                                                                        \
    } while (0)

    u32x4 b0[4], b1[4];
    LOADB(b0, 0);
    LOADB(b1, 1);          // nt >= 21 always, so tile 1 exists

    int t = 0;
    for (; t + 2 < nt; t += 2) {
        COMPUTE(b0);
        LOADB(b0, t + 2);
        COMPUTE(b1);
        if (t + 3 < nt) LOADB(b1, t + 3);
    }
    COMPUTE(b0);
    if (t + 1 < nt) COMPUTE(b1);

#undef LOADB
#undef COMPUTE

    // reduce row-sums across the 16 column-lanes; write per-split partials
#pragma unroll
    for (int rt = 0; rt < 4; ++rt)
#pragma unroll
        for (int r = 0; r < 4; ++r) {
            float s = rs[rt][r];
            s += __shfl_xor(s, 1);  s += __shfl_xor(s, 2);
            s += __shfl_xor(s, 4);  s += __shfl_xor(s, 8);
            if (lo16 == 0) {
                int row = rowBase + rt * 16 + hi4 * 4 + r;
                partial[blockIdx.y * NROWS + row] = s;
            }
        }
}

// ---- kernel 3: per-row lse - pos, subtract diag, block partial sums --------
__global__ __launch_bounds__(256) void k_finalize(
    const uint16_t* __restrict__ znA, const uint16_t* __restrict__ znB,
    const float* __restrict__ partial, float* __restrict__ blocksum)
{
    int tid = threadIdx.x;
    int i = blockIdx.x * 256 + tid;

    float S = 0.f;
#pragma unroll
    for (int cs = 0; cs < CSPL; ++cs) S += partial[cs * NROWS + i];

    int j = (i + BROWS) & (NROWS - 1);
    const uint4* rAi = (const uint4*)((const char*)znA + (size_t)i * ROWB);
    const uint4* rBi = (const uint4*)((const char*)znB + (size_t)i * ROWB);
    const uint4* rBj = (const uint4*)((const char*)znB + (size_t)j * ROWB);
    float adot = 0.f;   // K1 * <zn_i, zn_j>
    float sdot = 0.f;   // K1 * <zn_i, zn_i>
#pragma unroll
    for (int c = 0; c < 16; ++c) {
        uint4 ua = rAi[c], ub = rBi[c], vb = rBj[c];
        const uint32_t* pa = (const uint32_t*)&ua;
        const uint32_t* pb = (const uint32_t*)&ub;
        const uint32_t* pv = (const uint32_t*)&vb;
#pragma unroll
        for (int q = 0; q < 4; ++q) {
            float a0 = bf2f((uint16_t)(pa[q] & 0xffffu)), a1 = bf2f((uint16_t)(pa[q] >> 16));
            float b0 = bf2f((uint16_t)(pb[q] & 0xffffu)), b1 = bf2f((uint16_t)(pb[q] >> 16));
            float v0 = bf2f((uint16_t)(pv[q] & 0xffffu)), v1 = bf2f((uint16_t)(pv[q] >> 16));
            adot += a0 * v0 + a1 * v1;
            sdot += a0 * b0 + a1 * b1;
        }
    }
    S -= __builtin_amdgcn_exp2f(sdot);                  // remove diagonal term
    float c = LN2F * (__builtin_amdgcn_logf(S) - adot); // ln(S) - pos/T

#pragma unroll
    for (int off = 1; off < 64; off <<= 1) c += __shfl_xor(c, off);
    __shared__ float wsum[4];
    int lane = tid & 63, wid = tid >> 6;
    if (lane == 0) wsum[wid] = c;
    __syncthreads();
    if (tid == 0) blocksum[blockIdx.x] = wsum[0] + wsum[1] + wsum[2] + wsum[3];
}

// ---- kernel 4: final scalar -------------------------------------------------
__global__ __launch_bounds__(64) void k_reduce(
    const float* __restrict__ blocksum, float* __restrict__ out)
{
    int tid = threadIdx.x;
    float v = (tid < 32) ? blocksum[tid] : 0.f;
#pragma unroll
    for (int off = 1; off < 64; off <<= 1) v += __shfl_xor(v, off);
    if (tid == 0) out[0] = v * (1.0f / (float)NROWS);
}

extern "C" void kernel_launch(void* const* d_in, const int* in_sizes, int n_in,
                              void* d_out, int out_size, void* d_ws, size_t ws_size,
                              hipStream_t stream)
{
    const float* zi = (const float*)d_in[0];
    const float* zj = (const float*)d_in[1];
    float* out = (float*)d_out;

    char* ws = (char*)d_ws;
    uint16_t* znA      = (uint16_t*)ws;                                   // 2 MB
    uint16_t* znB      = (uint16_t*)(ws + (size_t)NROWS * ROWB);          // 2 MB
    float*    partial  = (float*)(ws + 2 * (size_t)NROWS * ROWB);         // 768 KB
    float*    blocksum = (float*)(ws + 2 * (size_t)NROWS * ROWB
                                     + (size_t)CSPL * NROWS * 4);

    k_normalize<<<dim3(256), dim3(256), 0, stream>>>(zi, zj, znA, znB);
    k_simlse  <<<dim3(32, CSPL), dim3(256), 0, stream>>>(znA, znB, partial);
    k_finalize<<<dim3(32), dim3(256), 0, stream>>>(znA, znB, partial, blocksum);
    k_reduce  <<<dim3(1), dim3(64), 0, stream>>>(blocksum, out);
}